// Round 1
// baseline (761.515 us; speedup 1.0000x reference)
//
#include <hip/hip_runtime.h>

// ---------------------------------------------------------------------------
// ChemistryAwareDecoder on MI355X (gfx950)
// N=100000 nodes, E=200000 edges, SD=128, CD=768
// Strategy: fused block-diagonal GEMM [E x 896] @ [896 x 384] with bf16x3
// error-compensated MFMA (f32-grade accuracy), fused epilogue.
// ---------------------------------------------------------------------------

typedef float  f32x4  __attribute__((ext_vector_type(4)));
typedef __bf16 bf16x8 __attribute__((ext_vector_type(8)));
typedef unsigned short u16x4 __attribute__((ext_vector_type(4)));

static_assert(sizeof(bf16x8) == 16, "bf16x8 must be 16B");
static_assert(sizeof(f32x4) == 16, "f32x4 must be 16B");

#define N_NODES 100000
#define E_EDGES 200000
#define KSTEPS  28                  // 896 / 32
#define NOUT    384                 // 64 + 192 + 128 fused outputs
#define PTOT    (KSTEPS * NOUT * 32)  // 344064 weight elements

// workspace layout (bytes)
#define WS_WHI   0
#define WS_WLO   688128
#define WS_B1    1376256
#define WS_W2    1377792
#define WS_CONST 1379328

__device__ __forceinline__ unsigned short f2bf(float f) {
  unsigned int x = __float_as_uint(f);
  unsigned int r = (x + 0x7FFFu + ((x >> 16) & 1u)) >> 16;  // RNE
  return (unsigned short)r;
}
__device__ __forceinline__ float bf2f(unsigned short u) {
  return __uint_as_float(((unsigned int)u) << 16);
}

// ---------------------------------------------------------------------------
// Prep: build fused block-diagonal weight panels (pre-transposed, pre-split),
// fused bias/layer-2 vectors, softmax consts, and edge-dtype detection flag.
// Panel layout: whi[p][n][kk]  (p = k-chunk of 32, n = 0..383, kk = 0..31)
// Wbig[k][n]: n<64: sw1 (k<128) | n<256: cw1 (k>=128) | n>=256: mw1 (all k)
// ---------------------------------------------------------------------------
__global__ __launch_bounds__(256) void prep_kernel(
    const float* __restrict__ sw1, const float* __restrict__ sb1,
    const float* __restrict__ sw2, const float* __restrict__ sb2,
    const float* __restrict__ cw1, const float* __restrict__ cb1,
    const float* __restrict__ cw2, const float* __restrict__ cb2,
    const float* __restrict__ mw1, const float* __restrict__ mb1,
    const float* __restrict__ mw2, const float* __restrict__ mb2,
    const float* __restrict__ pw,  const int* __restrict__ edge_i32,
    unsigned short* __restrict__ whi, unsigned short* __restrict__ wlo,
    float* __restrict__ b1cat, float* __restrict__ w2cat,
    float* __restrict__ consts)
{
  const int idx = blockIdx.x * 256 + threadIdx.x;
  if (idx < PTOT) {
    const int p  = idx / (NOUT * 32);
    const int r  = idx % (NOUT * 32);
    const int n  = r >> 5;
    const int kk = r & 31;
    const int k  = p * 32 + kk;
    float v;
    if (n < 64)       v = (k < 128)  ? sw1[k * 64 + n] : 0.0f;
    else if (n < 256) v = (k >= 128) ? cw1[(size_t)(k - 128) * 192 + (n - 64)] : 0.0f;
    else              v = mw1[(size_t)k * 128 + (n - 256)];
    const unsigned short hi = f2bf(v);
    const unsigned short lo = f2bf(v - bf2f(hi));
    whi[idx] = hi;
    wlo[idx] = lo;
  } else if (idx < PTOT + NOUT) {
    const int j = idx - PTOT;
    float b, w;
    if (j < 64)       { b = sb1[j];       w = sw2[j]; }
    else if (j < 256) { b = cb1[j - 64];  w = cw2[j - 64]; }
    else              { b = mb1[j - 256]; w = mw2[j - 256]; }
    b1cat[j] = b;
    w2cat[j] = w;
  } else if (idx == PTOT + NOUT) {
    // softmax of path_weights
    const float p0 = pw[0], p1 = pw[1], p2 = pw[2];
    const float mx = fmaxf(p0, fmaxf(p1, p2));
    const float e0 = __expf(p0 - mx), e1 = __expf(p1 - mx), e2 = __expf(p2 - mx);
    const float inv = 1.0f / (e0 + e1 + e2);
    const float w0 = e0 * inv, w1 = e1 * inv, w2v = e2 * inv;
    consts[0] = w0; consts[1] = w1; consts[2] = w2v;
    consts[3] = w0 * sb2[0] + w1 * cb2[0] + w2v * mb2[0];  // valid-path bias
    consts[4] = sb2[0];                                    // invalid-path bias
    // edge dtype detection: int64 little-endian => all odd 32-bit words zero
    unsigned o = 0;
    for (int i = 0; i < 64; ++i) o |= (unsigned)edge_i32[2 * i + 1];
    consts[5] = (o == 0u) ? 1.0f : 0.0f;  // 1 => int64 layout
  }
}

// ---------------------------------------------------------------------------
// Main: 64 edges/block, 256 threads (4 waves). Waves stripe N-tiles
// (ti = wave + 4*i) for zero-block load balance. Per K-step (32):
//   A-tile (products, bf16 hi/lo) double-buffered in LDS (stride 40: 2-way)
//   B-frags straight from global panels (L2-hot, 1KB coalesced per frag)
//   3 MFMAs per tile (hi*hi + hi*lo + lo*hi)
// Epilogue: bias+ReLU+w2 dot + per-edge path weighting, 16-lane shfl reduce,
// LDS atomic combine across waves.
// ---------------------------------------------------------------------------
__global__ __launch_bounds__(256, 2) void decoder_main(
    const float* __restrict__ z, const float* __restrict__ chem,
    const int* __restrict__ edge, const int* __restrict__ mask,
    const unsigned short* __restrict__ whi, const unsigned short* __restrict__ wlo,
    const float* __restrict__ b1cat, const float* __restrict__ w2cat,
    const float* __restrict__ consts, float* __restrict__ out)
{
  __shared__ unsigned short Ah[2][64][40];  // +8 pad: 2-way banks (free)
  __shared__ unsigned short Al[2][64][40];
  __shared__ int   srcL[64];
  __shared__ int   dstL[64];
  __shared__ float validL[64];
  __shared__ float scoreL[64];

  const int tid  = threadIdx.x;
  const int lane = tid & 63;
  const int wv   = tid >> 6;       // wave 0..3
  const int li   = lane & 15;
  const int q    = lane >> 4;      // quad 0..3
  const int m0   = blockIdx.x << 6;

  if (tid < 64) {
    scoreL[tid] = 0.0f;
    const int e = m0 + tid;
    int s_, d_;
    if (consts[5] > 0.5f) { s_ = edge[4 * e]; d_ = edge[4 * e + 2]; }  // int64
    else                  { s_ = edge[2 * e]; d_ = edge[2 * e + 1]; }  // int32
    srcL[tid] = s_;
    dstL[tid] = d_;
    validL[tid] = (mask[s_] != 0 && mask[d_] != 0) ? 1.0f : 0.0f;
  }
  __syncthreads();

  // fixed per-thread staging slots: 2 edges x 4 k-values each K-step
  const int mA = tid >> 3;
  const int mB = 32 + mA;
  const int kc = (tid & 7) << 2;
  const float* zsA = z + (size_t)srcL[mA] * 128 + kc;
  const float* zdA = z + (size_t)dstL[mA] * 128 + kc;
  const float* zsB = z + (size_t)srcL[mB] * 128 + kc;
  const float* zdB = z + (size_t)dstL[mB] * 128 + kc;
  const float* csA = chem + (size_t)srcL[mA] * 768 + kc;
  const float* cdA = chem + (size_t)dstL[mA] * 768 + kc;
  const float* csB = chem + (size_t)srcL[mB] * 768 + kc;
  const float* cdB = chem + (size_t)dstL[mB] * 768 + kc;

  auto split_store = [&](int buf, int m, f32x4 p) {
    u16x4 h, l;
#pragma unroll
    for (int j = 0; j < 4; ++j) {
      const unsigned short hj = f2bf(p[j]);
      h[j] = hj;
      l[j] = f2bf(p[j] - bf2f(hj));
    }
    *(u16x4*)&Ah[buf][m][kc] = h;
    *(u16x4*)&Al[buf][m][kc] = l;
  };

  // stage step 0 (k0 = 0: from z)
  {
    const f32x4 a0 = *(const f32x4*)zsA;
    const f32x4 b0 = *(const f32x4*)zdA;
    const f32x4 a1 = *(const f32x4*)zsB;
    const f32x4 b1 = *(const f32x4*)zdB;
    split_store(0, mA, a0 * b0);
    split_store(0, mB, a1 * b1);
  }
  __syncthreads();

  f32x4 acc[4][6];
#pragma unroll
  for (int mt = 0; mt < 4; ++mt)
#pragma unroll
    for (int i = 0; i < 6; ++i)
      acc[mt][i] = (f32x4){0.f, 0.f, 0.f, 0.f};

  for (int s = 0; s < KSTEPS; ++s) {
    const int buf = s & 1;

    // A fragments from LDS: lane holds A[m = mt*16+li][k = q*8 + j]
    bf16x8 afh[4], afl[4];
#pragma unroll
    for (int mt = 0; mt < 4; ++mt) {
      afh[mt] = *(const bf16x8*)&Ah[buf][mt * 16 + li][q * 8];
      afl[mt] = *(const bf16x8*)&Al[buf][mt * 16 + li][q * 8];
    }

    // B fragments from global panels (issued BEFORE gathers: in-order vmcnt)
    bf16x8 bfh[6], bfl[6];
    bool act[6];
#pragma unroll
    for (int i = 0; i < 6; ++i) {
      const int ti = wv + 4 * i;
      const int path = (ti < 4) ? 0 : (ti < 16 ? 1 : 2);
      act[i] = (path == 0) ? (s < 4) : (path == 1) ? (s >= 4) : true;
      if (act[i]) {
        const size_t off = (size_t)s * (NOUT * 32) + (size_t)(ti * 16 + li) * 32 + q * 8;
        bfh[i] = *(const bf16x8*)(whi + off);
        bfl[i] = *(const bf16x8*)(wlo + off);
      }
    }

    // prefetch gathers for next K-step (latency hidden by MFMAs below)
    f32x4 ga, gb, gc, gd;
    if (s + 1 < KSTEPS) {
      const int k0 = (s + 1) * 32;
      if (k0 < 128) {
        ga = *(const f32x4*)(zsA + k0); gb = *(const f32x4*)(zdA + k0);
        gc = *(const f32x4*)(zsB + k0); gd = *(const f32x4*)(zdB + k0);
      } else {
        const int ko = k0 - 128;
        ga = *(const f32x4*)(csA + ko); gb = *(const f32x4*)(cdA + ko);
        gc = *(const f32x4*)(csB + ko); gd = *(const f32x4*)(cdB + ko);
      }
    }

    // bf16x3 compensated MFMA
#pragma unroll
    for (int i = 0; i < 6; ++i) {
      if (act[i]) {
#pragma unroll
        for (int mt = 0; mt < 4; ++mt) {
          acc[mt][i] = __builtin_amdgcn_mfma_f32_16x16x32_bf16(afh[mt], bfh[i], acc[mt][i], 0, 0, 0);
          acc[mt][i] = __builtin_amdgcn_mfma_f32_16x16x32_bf16(afh[mt], bfl[i], acc[mt][i], 0, 0, 0);
          acc[mt][i] = __builtin_amdgcn_mfma_f32_16x16x32_bf16(afl[mt], bfh[i], acc[mt][i], 0, 0, 0);
        }
      }
    }

    // stage next tile into the other buffer
    if (s + 1 < KSTEPS) {
      const int nbuf = buf ^ 1;
      split_store(nbuf, mA, ga * gb);
      split_store(nbuf, mB, gc * gd);
    }
    __syncthreads();
  }

  // ---------------- epilogue ----------------
  float part[4][4];
#pragma unroll
  for (int mt = 0; mt < 4; ++mt)
#pragma unroll
    for (int r = 0; r < 4; ++r) part[mt][r] = 0.f;

  const float w0c = consts[0], w1c = consts[1], w2c = consts[2];
#pragma unroll
  for (int i = 0; i < 6; ++i) {
    const int ti = wv + 4 * i;
    const int path = (ti < 4) ? 0 : (ti < 16 ? 1 : 2);
    const int col = ti * 16 + li;
    const float b1 = b1cat[col];
    const float w2 = w2cat[col];
    const float wp  = (path == 0) ? w0c : (path == 1) ? w1c : w2c;
    const float p0f = (path == 0) ? 1.0f : 0.0f;
#pragma unroll
    for (int mt = 0; mt < 4; ++mt) {
#pragma unroll
      for (int r = 0; r < 4; ++r) {
        const float valid = validL[mt * 16 + q * 4 + r];
        const float a = p0f + valid * (wp - p0f);  // valid ? w[path] : (path==0)
        float v = acc[mt][i][r] + b1;
        v = fmaxf(v, 0.0f);
        part[mt][r] += a * v * w2;
      }
    }
  }

  // sum across the 16 lanes of each quad (cols), then combine across waves
#pragma unroll
  for (int mt = 0; mt < 4; ++mt) {
#pragma unroll
    for (int r = 0; r < 4; ++r) {
      float v = part[mt][r];
      v += __shfl_xor(v, 1);
      v += __shfl_xor(v, 2);
      v += __shfl_xor(v, 4);
      v += __shfl_xor(v, 8);
      if (li == 0) atomicAdd(&scoreL[mt * 16 + q * 4 + r], v);
    }
  }
  __syncthreads();

  if (tid < 64) {
    const float valid = validL[tid];
    const float cadd = consts[4] + valid * (consts[3] - consts[4]);
    out[m0 + tid] = scoreL[tid] + cadd;
  }
}

// ---------------------------------------------------------------------------
extern "C" void kernel_launch(void* const* d_in, const int* in_sizes, int n_in,
                              void* d_out, int out_size, void* d_ws, size_t ws_size,
                              hipStream_t stream)
{
  const float* z    = (const float*)d_in[0];
  const float* chem = (const float*)d_in[1];
  const int*   edge = (const int*)d_in[2];
  const int*   mask = (const int*)d_in[3];
  const float* sw1  = (const float*)d_in[4];
  const float* sb1  = (const float*)d_in[5];
  const float* sw2  = (const float*)d_in[6];
  const float* sb2  = (const float*)d_in[7];
  const float* cw1  = (const float*)d_in[8];
  const float* cb1  = (const float*)d_in[9];
  const float* cw2  = (const float*)d_in[10];
  const float* cb2  = (const float*)d_in[11];
  const float* mw1  = (const float*)d_in[12];
  const float* mb1  = (const float*)d_in[13];
  const float* mw2  = (const float*)d_in[14];
  const float* mb2  = (const float*)d_in[15];
  const float* pw   = (const float*)d_in[16];

  char* ws = (char*)d_ws;
  unsigned short* whi = (unsigned short*)(ws + WS_WHI);
  unsigned short* wlo = (unsigned short*)(ws + WS_WLO);
  float* b1cat  = (float*)(ws + WS_B1);
  float* w2cat  = (float*)(ws + WS_W2);
  float* consts = (float*)(ws + WS_CONST);

  const int prep_tasks  = PTOT + NOUT + 64;  // panels + bias/w2 + consts
  const int prep_blocks = (prep_tasks + 255) / 256;
  prep_kernel<<<prep_blocks, 256, 0, stream>>>(
      sw1, sb1, sw2, sb2, cw1, cb1, cw2, cb2, mw1, mb1, mw2, mb2, pw, edge,
      whi, wlo, b1cat, w2cat, consts);

  decoder_main<<<E_EDGES / 64, 256, 0, stream>>>(
      z, chem, edge, mask, whi, wlo, b1cat, w2cat, consts, (float*)d_out);
}